// Round 1
// 463.609 us; speedup vs baseline: 1.1580x; 1.1580x over previous
//
#include <hip/hip_runtime.h>
#include <math.h>

// StackedLSTM: B=2048, T=2048, D=H=6, 2 layers, softmax(h_last) -> [2048, 6] fp32.
//
// R3: latency-chain attack. 1024 waves = 1 wave/SIMD, so wall time = 2049 x
// per-step chain latency. R2 spent ~12 ds_bpermute/step (LDS-crossbar pipe,
// ~60-120cy + lgkmcnt drain) on the h broadcast. R3 makes the recurrence
// 100% VALU:
//   - NEW LANE LAYOUT: l = lane>>5 (layer in bit5!), s = (lane>>4)&1 (slot),
//     j = (lane>>1)&7 (unit, 6..7 dummy), p = lane&1 (gate pair).
//   - cross-layer h0 -> layer1: ONE v_permlane32_swap (VALU) instead of 6
//     bpermutes.  [RISK A: if r[0] is not {lo,lo}, use r[1] instead]
//   - recurrence dot via DPP ring: 7 independent row_ror:{2..14} of hv give
//     each lane all 8 ring values; weights pre-rotated per lane:
//     w[r] = W[row][(j-r)&7], 0 for idx>=6 (so dummy-lane garbage h is
//     annihilated by the weight, no zeroing needed).
//     [RISK B: assumes ror:n => dst[i]=src[(i-n)&15] (row_shr scan idiom);
//      if flipped, change weight index to (j+r)&7]
//   - exp2-domain scales folded into weights/biases (no sA*kAl mul); c kept
//     in 2*LOG2E domain (no cn*2LOG2E mul); i-gate carries the K2 scale.
//   - t=0 layer-1 zeroing peeled out of the loop (no per-step ok-select).
// x staging: unchanged double-buffered LDS (32 steps/block), plus a 1-step
// register prefetch of the per-lane x_j (one ds_read_b32/step, off-chain).

#define TSTEPS 2048
#define LOG2E 1.442695040889f

__device__ __forceinline__ float fast_rcp(float v) { return __builtin_amdgcn_rcpf(v); }

template <int CTRL>
__device__ __forceinline__ float dpp_f(float v) {
    return __int_as_float(__builtin_amdgcn_mov_dpp(__float_as_int(v), CTRL, 0xF, 0xF, true));
}

#if __has_builtin(__builtin_amdgcn_exp2f)
#define EXP2F(x) __builtin_amdgcn_exp2f(x)
#else
#define EXP2F(x) __expf((x) * 0.69314718056f)
#endif

typedef int int2v __attribute__((ext_vector_type(2)));

// Broadcast lower-half (layer-0) lanes' value to the upper-half (layer-1)
// lanes at lane-32 offset. Lower lanes get their own value back (unused).
__device__ __forceinline__ float layer_swap_lo(float v, int swapaddr) {
#if __has_builtin(__builtin_amdgcn_permlane32_swap)
    (void)swapaddr;
    int2v r = __builtin_amdgcn_permlane32_swap(__float_as_int(v), __float_as_int(v),
                                               false, false);
    // new vdst = {vdst.rows01, vsrc.rows01} = {v.lo, v.lo}: upper lanes see
    // hv[lane-32] = layer-0's h at the same (s,j,p).  [RISK A: else r[1]]
    return __int_as_float(r[0]);
#else
    return __int_as_float(__builtin_amdgcn_ds_bpermute(swapaddr, __float_as_int(v)));
#endif
}

__global__ __launch_bounds__(64, 1)
void stacked_lstm_kernel(const float* __restrict__ x,
                         const float* __restrict__ Wih0, const float* __restrict__ Whh0,
                         const float* __restrict__ bih0, const float* __restrict__ bhh0,
                         const float* __restrict__ Wih1, const float* __restrict__ Whh1,
                         const float* __restrict__ bih1, const float* __restrict__ bhh1,
                         float* __restrict__ out)
{
    __shared__ __align__(16) float Xs[2][2][192];  // [slot][buf][32 steps * 6]
    __shared__ float Hb[2][8];                     // [slot][8] h1_last for epilogue

    const int lane = threadIdx.x;
    const int l = lane >> 5;            // layer (bit 5 -> permlane32_swap crosses it)
    const int s = (lane >> 4) & 1;      // batch slot within wave
    const int j = (lane >> 1) & 7;      // unit 0..7 (6,7 dummy)
    const int p = lane & 1;             // gate pair: 0 -> (i,f), 1 -> (g,o)
    const int jc = (j < 6) ? j : 5;
    const int w12 = lane & 15;
    const bool loader = (l == 0) && (w12 < 12);
    const long b = (long)blockIdx.x * 2 + s;
    const int swapaddr = (lane ^ 32) << 2;  // only used by bpermute fallback

    const float* Wih = l ? Wih1 : Wih0;
    const float* Whh = l ? Whh1 : Whh0;
    const float* bih = l ? bih1 : bih0;
    const float* bhh = l ? bhh1 : bhh0;

    // PyTorch gate-order rows: i=0..5, f=6..11, g=12..17, o=18..23
    const int rowA = p * 12 + jc;       // p=0: i-row ; p=1: g-row
    const int rowB = rowA + 6;          // p=0: f-row ; p=1: o-row

    // exp2-domain scales folded into weights+biases:
    //   i,f,o rows (sigmoid): LOG2E ; g row (tanh): 2*LOG2E
    const float scaleA = p ? (2.0f * LOG2E) : LOG2E;
    const float scaleB = LOG2E;

    // Pre-rotated weight tables: entry r multiplies the ring value h_{(j-r)&7}.
    float wiA[8], whA[8], wiB[8], whB[8];
#pragma unroll
    for (int r = 0; r < 8; ++r) {
        const int idx = (j - r) & 7;
        const bool okw = idx < 6;
        const int ic = okw ? idx : 0;   // keep loads in-bounds
        wiA[r] = okw ? Wih[rowA * 6 + ic] * scaleA : 0.0f;
        whA[r] = okw ? Whh[rowA * 6 + ic] * scaleA : 0.0f;
        wiB[r] = okw ? Wih[rowB * 6 + ic] * scaleB : 0.0f;
        whB[r] = okw ? Whh[rowB * 6 + ic] * scaleB : 0.0f;
    }
    const float bA2 = (bih[rowA] + bhh[rowA]) * scaleA;
    const float bB2 = (bih[rowB] + bhh[rowB]) * scaleB;
    // Activation row A: p=0 -> K2*sigmoid(i) (carries the 2*LOG2E c-domain
    // scale), p=1 -> tanh(g).  act = fma(mA, -rcp(1+e), nA).
    const float K2 = 2.0f * LOG2E;
    const float mA = p ? 2.0f : K2;
    const float nA = p ? 1.0f : K2;

    // ---- x staging: 32 steps (768 B) per slot, loaded by 12 lanes per slot ----
    const float* xb = x + b * (TSTEPS * 6);
    float4 pre0, pre1, pre2, pre3;

    auto LOADBLK = [&](int blk) {
        if (loader) {
            const float4* xv = (const float4*)(xb + blk * 192);
            pre0 = xv[w12 +  0];
            pre1 = xv[w12 + 12];
            pre2 = xv[w12 + 24];
            pre3 = xv[w12 + 36];
        }
    };
    auto WRITEBLK = [&](int buf) {
        if (loader) {
            float4* dst = (float4*)&Xs[s][buf][0];
            dst[w12 +  0] = pre0;
            dst[w12 + 12] = pre1;
            dst[w12 + 24] = pre2;
            dst[w12 + 36] = pre3;
        }
    };

    LOADBLK(0);
    WRITEBLK(0);
    LOADBLK(1);
    __builtin_amdgcn_wave_barrier();

    // Per-lane x pointer: lane (j,p) reads x_t[jc] each step; prefetched 1 ahead.
    const float* xpp = &Xs[s][0][jc];
    float xcur = *xpp;

    float hv = 0.0f;   // own-layer h_j (valid on both pair lanes)
    float c  = 0.0f;   // cell state, kept in 2*LOG2E domain

    // Iter t: layer0 computes h0(t), layer1 computes h1(t-1) (one step behind).
    auto body = [&](int t) {
        const int row = t & 31;
        if (row == 0 && t > 0) {
            const int blk = t >> 5;
            const int buf = blk & 1;
            if (blk <= 63) {
                WRITEBLK(buf);
                if (blk < 63) LOADBLK(blk + 1);
            }
            __builtin_amdgcn_wave_barrier();
            xpp = &Xs[s][buf][jc];
            xcur = *xpp;
        }
        // prefetch next step's x (row31 re-reads current: harmless, unused)
        float xnext = xpp[(row < 31) ? 6 : 0];

        // cross-layer: layer-1 lanes receive h0(t-1); layer-0 keeps own (unused)
        float h0bc = layer_swap_lo(hv, swapaddr);
        float inv = l ? h0bc : xcur;

        // DPP ring: all independent off hv / inv (lane j sees h_{(j-r)&7})
        float h1r = dpp_f<0x122>(hv);
        float h2r = dpp_f<0x124>(hv);
        float h3r = dpp_f<0x126>(hv);
        float h4r = dpp_f<0x128>(hv);
        float h5r = dpp_f<0x12A>(hv);
        float h6r = dpp_f<0x12C>(hv);
        float h7r = dpp_f<0x12E>(hv);
        float i1r = dpp_f<0x122>(inv);
        float i2r = dpp_f<0x124>(inv);
        float i3r = dpp_f<0x126>(inv);
        float i4r = dpp_f<0x128>(inv);
        float i5r = dpp_f<0x12A>(inv);
        float i6r = dpp_f<0x12C>(inv);
        float i7r = dpp_f<0x12E>(inv);

        // row A sum (4 parallel chains of 4)
        float a1 = fmaf(hv,  whA[0], bA2);
        a1 = fmaf(h1r, whA[1], a1);
        a1 = fmaf(h2r, whA[2], a1);
        a1 = fmaf(h3r, whA[3], a1);
        float a2 = h4r * whA[4];
        a2 = fmaf(h5r, whA[5], a2);
        a2 = fmaf(h6r, whA[6], a2);
        a2 = fmaf(h7r, whA[7], a2);
        float a3 = inv * wiA[0];
        a3 = fmaf(i1r, wiA[1], a3);
        a3 = fmaf(i2r, wiA[2], a3);
        a3 = fmaf(i3r, wiA[3], a3);
        float a4 = i4r * wiA[4];
        a4 = fmaf(i5r, wiA[5], a4);
        a4 = fmaf(i6r, wiA[6], a4);
        a4 = fmaf(i7r, wiA[7], a4);
        float sA = (a1 + a2) + (a3 + a4);

        // row B sum
        float c1 = fmaf(hv,  whB[0], bB2);
        c1 = fmaf(h1r, whB[1], c1);
        c1 = fmaf(h2r, whB[2], c1);
        c1 = fmaf(h3r, whB[3], c1);
        float c2 = h4r * whB[4];
        c2 = fmaf(h5r, whB[5], c2);
        c2 = fmaf(h6r, whB[6], c2);
        c2 = fmaf(h7r, whB[7], c2);
        float c3 = inv * wiB[0];
        c3 = fmaf(i1r, wiB[1], c3);
        c3 = fmaf(i2r, wiB[2], c3);
        c3 = fmaf(i3r, wiB[3], c3);
        float c4 = i4r * wiB[4];
        c4 = fmaf(i5r, wiB[5], c4);
        c4 = fmaf(i6r, wiB[6], c4);
        c4 = fmaf(i7r, wiB[7], c4);
        float sB = (c1 + c2) + (c3 + c4);

        // activations (scales pre-folded into weights: exp args are ready)
        float eA = EXP2F(sA);
        float gA = fmaf(mA, -fast_rcp(1.0f + eA), nA);  // p=0: K2*sig(i), p=1: tanh(g)
        float eB = EXP2F(sB);
        float gB = 1.0f - fast_rcp(1.0f + eB);          // sigmoid (f or o)

        // pair exchange (lane^1) and cell update (c in K2 domain)
        float xA = dpp_f<0xB1>(gA);
        float xB = dpp_f<0xB1>(gB);
        float ig = gA * xA;                 // = K2 * i * g on both pair lanes
        float gf = p ? xB : gB;             // sigmoid(f)
        float go = p ? gB : xB;             // sigmoid(o)
        c = fmaf(gf, c, ig);
        float ec = EXP2F(c);                // = e^{2*c_true}
        float th = fmaf(2.0f, -fast_rcp(1.0f + ec), 1.0f); // tanh(c_true)
        hv = go * th;

        xcur = xnext;
        xpp += 6;
    };

    body(0);
    // layer-1's iter-0 step is fictitious: zero its state once (off the loop)
    if (l) { hv = 0.0f; c = 0.0f; }
    for (int t = 1; t <= TSTEPS; ++t) body(t);

    // ---- epilogue: hv on layer-1 lanes is h1(T-1); softmax over it ----
    if (l == 1 && p == 0 && j < 6) Hb[s][j] = hv;
    __builtin_amdgcn_wave_barrier();

    if (l == 0 && w12 < 6) {
        const float* hp = &Hb[s][0];
        float2 u0 = *(const float2*)(hp + 0);
        float2 u1 = *(const float2*)(hp + 2);
        float2 u2 = *(const float2*)(hp + 4);
        float v0 = u0.x, v1 = u0.y, v2 = u1.x, v3 = u1.y, v4 = u2.x, v5 = u2.y;
        float m = fmaxf(fmaxf(fmaxf(v0, v1), fmaxf(v2, v3)), fmaxf(v4, v5));
        float e0 = __expf(v0 - m), e1 = __expf(v1 - m), e2 = __expf(v2 - m);
        float e3 = __expf(v3 - m), e4 = __expf(v4 - m), e5 = __expf(v5 - m);
        float sum = ((e0 + e1) + (e2 + e3)) + (e4 + e5);
        float r = fast_rcp(sum);
        float mine = (w12 == 0) ? e0 : (w12 == 1) ? e1 : (w12 == 2) ? e2
                   : (w12 == 3) ? e3 : (w12 == 4) ? e4 : e5;
        out[b * 6 + w12] = mine * r;
    }
}

extern "C" void kernel_launch(void* const* d_in, const int* in_sizes, int n_in,
                              void* d_out, int out_size, void* d_ws, size_t ws_size,
                              hipStream_t stream) {
    (void)in_sizes; (void)n_in; (void)d_ws; (void)ws_size; (void)out_size;
    const float* x    = (const float*)d_in[0];
    const float* Wih0 = (const float*)d_in[1];
    const float* Whh0 = (const float*)d_in[2];
    const float* bih0 = (const float*)d_in[3];
    const float* bhh0 = (const float*)d_in[4];
    const float* Wih1 = (const float*)d_in[5];
    const float* Whh1 = (const float*)d_in[6];
    const float* bih1 = (const float*)d_in[7];
    const float* bhh1 = (const float*)d_in[8];
    float* outp = (float*)d_out;

    // 2048 batch / 2 per wave = 1024 blocks of 64 threads = 1 wave per SIMD.
    stacked_lstm_kernel<<<1024, 64, 0, stream>>>(
        x, Wih0, Whh0, bih0, bhh0, Wih1, Whh1, bih1, bhh1, outp);
}

// Round 2
// 384.485 us; speedup vs baseline: 1.3963x; 1.2058x over previous
//
#include <hip/hip_runtime.h>
#include <math.h>

// StackedLSTM: B=2048, T=2048, D=H=6, 2 layers, softmax(h_last) -> [2048, 6] fp32.
//
// R4: issue-count attack (R3 measured 283 VALU-busy cy/step vs ~150 semantic).
//   - Packed fp32: dot products pair along k. Ring values coalesce into
//     float2 pairs {hv,h1r},{h2r,h3r},... (no broadcast movs); weights are
//     persistent float2 pairs. 32 fma + 6 add -> 16 v_pk_fma + 2 pk_add +
//     2 horizontal adds. Written as ext_vector float2 ops so the backend
//     selects v_pk_fma_f32 (gfx90a+ packed-FP32; falls back to scalar fma
//     with zero correctness risk if not).
//   - Full 32-step unroll per x-block (64 outer iters): row is compile-time,
//     ds_read_b32 gets static offset:, no per-step loop/address/select code.
//   - Xs padded 192->196 floats/buf: slots were 768B apart = same banks
//     (SQ_LDS_BANK_CONFLICT == 2*steps*blocks in R3). Now bank-shifted by 8.
// Lane layout, DPP ring, permlane32_swap, exp2-domain folding: unchanged
// from R3 (verified passing).

#define TSTEPS 2048
#define LOG2E 1.442695040889f

typedef __attribute__((ext_vector_type(2))) float f2;
typedef __attribute__((ext_vector_type(2))) int int2v;

__device__ __forceinline__ float fast_rcp(float v) { return __builtin_amdgcn_rcpf(v); }

template <int CTRL>
__device__ __forceinline__ float dpp_f(float v) {
    return __int_as_float(__builtin_amdgcn_mov_dpp(__float_as_int(v), CTRL, 0xF, 0xF, true));
}

#if __has_builtin(__builtin_amdgcn_exp2f)
#define EXP2F(x) __builtin_amdgcn_exp2f(x)
#else
#define EXP2F(x) __expf((x) * 0.69314718056f)
#endif

// Broadcast lower-half (layer-0) lanes' value to upper-half lanes at lane-32
// offset (verified orientation in R3).
__device__ __forceinline__ float layer_swap_lo(float v, int swapaddr) {
#if __has_builtin(__builtin_amdgcn_permlane32_swap)
    (void)swapaddr;
    int2v r = __builtin_amdgcn_permlane32_swap(__float_as_int(v), __float_as_int(v),
                                               false, false);
    return __int_as_float(r[0]);
#else
    return __int_as_float(__builtin_amdgcn_ds_bpermute(swapaddr, __float_as_int(v)));
#endif
}

__global__ __launch_bounds__(64, 1)
void stacked_lstm_kernel(const float* __restrict__ x,
                         const float* __restrict__ Wih0, const float* __restrict__ Whh0,
                         const float* __restrict__ bih0, const float* __restrict__ bhh0,
                         const float* __restrict__ Wih1, const float* __restrict__ Whh1,
                         const float* __restrict__ bih1, const float* __restrict__ bhh1,
                         float* __restrict__ out)
{
    // 196-float stride: slot offset = 392 floats -> bank shift 8 (no conflict).
    __shared__ __align__(16) float Xs[2][2][196];
    __shared__ float Hb[2][8];

    const int lane = threadIdx.x;
    const int l = lane >> 5;            // layer (bit 5: permlane32_swap crosses it)
    const int s = (lane >> 4) & 1;      // batch slot
    const int j = (lane >> 1) & 7;      // unit 0..7 (6,7 dummy)
    const int p = lane & 1;             // gate pair: 0 -> (i,f), 1 -> (g,o)
    const int jc = (j < 6) ? j : 5;
    const int w12 = lane & 15;
    const bool loader = (l == 0) && (w12 < 12);
    const long b = (long)blockIdx.x * 2 + s;
    const int swapaddr = (lane ^ 32) << 2;

    const float* Wih = l ? Wih1 : Wih0;
    const float* Whh = l ? Whh1 : Whh0;
    const float* bih = l ? bih1 : bih0;
    const float* bhh = l ? bhh1 : bhh0;

    const int rowA = p * 12 + jc;       // p=0: i-row ; p=1: g-row
    const int rowB = rowA + 6;          // p=0: f-row ; p=1: o-row
    const float scaleA = p ? (2.0f * LOG2E) : LOG2E;
    const float scaleB = LOG2E;

    // Pre-rotated weight PAIRS: pair r2 half h multiplies ring value (j-(2*r2+h))&7.
    f2 whA_p[4], wiA_p[4], whB_p[4], wiB_p[4];
#pragma unroll
    for (int r2 = 0; r2 < 4; ++r2) {
#pragma unroll
        for (int hf = 0; hf < 2; ++hf) {
            const int r = 2 * r2 + hf;
            const int idx = (j - r) & 7;
            const bool okw = idx < 6;
            const int ic = okw ? idx : 0;
            whA_p[r2][hf] = okw ? Whh[rowA * 6 + ic] * scaleA : 0.0f;
            wiA_p[r2][hf] = okw ? Wih[rowA * 6 + ic] * scaleA : 0.0f;
            whB_p[r2][hf] = okw ? Whh[rowB * 6 + ic] * scaleB : 0.0f;
            wiB_p[r2][hf] = okw ? Wih[rowB * 6 + ic] * scaleB : 0.0f;
        }
    }
    const f2 biasA = { (bih[rowA] + bhh[rowA]) * scaleA, 0.0f };
    const f2 biasB = { (bih[rowB] + bhh[rowB]) * scaleB, 0.0f };
    const float K2 = 2.0f * LOG2E;
    const float mA = p ? 2.0f : K2;     // p=0: K2*sigmoid(i) carries c-domain scale
    const float nA = p ? 1.0f : K2;

    // ---- x staging: 32 steps (768 B) per slot, 12 loader lanes per slot ----
    const float* xb = x + b * (TSTEPS * 6);
    float4 pre0, pre1, pre2, pre3;

    auto LOADBLK = [&](int blk) {
        if (loader) {
            const float4* xv = (const float4*)(xb + blk * 192);
            pre0 = xv[w12 +  0];
            pre1 = xv[w12 + 12];
            pre2 = xv[w12 + 24];
            pre3 = xv[w12 + 36];
        }
    };
    auto WRITEBLK = [&](int buf) {
        if (loader) {
            float4* dst = (float4*)&Xs[s][buf][0];
            dst[w12 +  0] = pre0;
            dst[w12 + 12] = pre1;
            dst[w12 + 24] = pre2;
            dst[w12 + 36] = pre3;
        }
    };

    float hv = 0.0f;   // own-layer h_j
    float c  = 0.0f;   // cell state, 2*LOG2E domain

    // One timestep. row is compile-time constant at every call site.
    auto STEP = [&](const float* xbase, int row) {
        float xcur = xbase[row * 6];                 // ds_read_b32 offset:row*24
        float h0bc = layer_swap_lo(hv, swapaddr);
        float inv  = l ? h0bc : xcur;

        float h1r = dpp_f<0x122>(hv);
        float h2r = dpp_f<0x124>(hv);
        float h3r = dpp_f<0x126>(hv);
        float h4r = dpp_f<0x128>(hv);
        float h5r = dpp_f<0x12A>(hv);
        float h6r = dpp_f<0x12C>(hv);
        float h7r = dpp_f<0x12E>(hv);
        float i1r = dpp_f<0x122>(inv);
        float i2r = dpp_f<0x124>(inv);
        float i3r = dpp_f<0x126>(inv);
        float i4r = dpp_f<0x128>(inv);
        float i5r = dpp_f<0x12A>(inv);
        float i6r = dpp_f<0x12C>(inv);
        float i7r = dpp_f<0x12E>(inv);

        f2 H01 = { hv,  h1r }, H23 = { h2r, h3r }, H45 = { h4r, h5r }, H67 = { h6r, h7r };
        f2 I01 = { inv, i1r }, I23 = { i2r, i3r }, I45 = { i4r, i5r }, I67 = { i6r, i7r };

        // Row A: h-chain (4 pk_fma, bias-seeded) + inv-chain (mul + 3 pk_fma)
        f2 aH = __builtin_elementwise_fma(H01, whA_p[0], biasA);
        aH = __builtin_elementwise_fma(H23, whA_p[1], aH);
        aH = __builtin_elementwise_fma(H45, whA_p[2], aH);
        aH = __builtin_elementwise_fma(H67, whA_p[3], aH);
        f2 aX = I01 * wiA_p[0];
        aX = __builtin_elementwise_fma(I23, wiA_p[1], aX);
        aX = __builtin_elementwise_fma(I45, wiA_p[2], aX);
        aX = __builtin_elementwise_fma(I67, wiA_p[3], aX);
        f2 SA2 = aH + aX;
        float sA = SA2.x + SA2.y;

        // Row B
        f2 bH = __builtin_elementwise_fma(H01, whB_p[0], biasB);
        bH = __builtin_elementwise_fma(H23, whB_p[1], bH);
        bH = __builtin_elementwise_fma(H45, whB_p[2], bH);
        bH = __builtin_elementwise_fma(H67, whB_p[3], bH);
        f2 bX = I01 * wiB_p[0];
        bX = __builtin_elementwise_fma(I23, wiB_p[1], bX);
        bX = __builtin_elementwise_fma(I45, wiB_p[2], bX);
        bX = __builtin_elementwise_fma(I67, wiB_p[3], bX);
        f2 SB2 = bH + bX;
        float sB = SB2.x + SB2.y;

        // activations (exp2-domain scales pre-folded)
        float eA = EXP2F(sA);
        float gA = fmaf(mA, -fast_rcp(1.0f + eA), nA);  // p=0: K2*sig(i), p=1: tanh(g)
        float eB = EXP2F(sB);
        float gB = 1.0f - fast_rcp(1.0f + eB);          // sigmoid (f or o)

        // pair exchange and cell update (c in K2 domain)
        float xA = dpp_f<0xB1>(gA);
        float xB = dpp_f<0xB1>(gB);
        float ig = gA * xA;                 // K2 * i * g
        float gf = p ? xB : gB;
        float go = p ? gB : xB;
        c = fmaf(gf, c, ig);
        float ec = EXP2F(c);                // e^{2*c_true}
        float th = fmaf(2.0f, -fast_rcp(1.0f + ec), 1.0f);
        hv = go * th;
    };

    // ---- prologue ----
    LOADBLK(0);
    WRITEBLK(0);
    LOADBLK(1);
    __builtin_amdgcn_wave_barrier();

    const float* xb0 = &Xs[s][0][jc];
    const float* xb1 = &Xs[s][1][jc];

    // t=0 (layer-1's step is fictitious: zero its state once, off the loop)
    STEP(xb0, 0);
    if (l) { hv = 0.0f; c = 0.0f; }
#pragma unroll
    for (int row = 1; row < 32; ++row) STEP(xb0, row);   // t=1..31

    for (int k = 1; k < 64; ++k) {
        const int buf = k & 1;
        WRITEBLK(buf);
        if (k < 63) LOADBLK(k + 1);
        __builtin_amdgcn_wave_barrier();
        const float* xbase = buf ? xb1 : xb0;
#pragma unroll
        for (int row = 0; row < 32; ++row) STEP(xbase, row);  // t=32k..32k+31
    }
    STEP(xb1, 0);   // t=2048: layer-0 output unused; layer-1 consumes h0(2047)

    // ---- epilogue: hv on layer-1 lanes is h1(T-1); softmax ----
    if (l == 1 && p == 0 && j < 6) Hb[s][j] = hv;
    __builtin_amdgcn_wave_barrier();

    if (l == 0 && w12 < 6) {
        const float* hp = &Hb[s][0];
        float2 u0 = *(const float2*)(hp + 0);
        float2 u1 = *(const float2*)(hp + 2);
        float2 u2 = *(const float2*)(hp + 4);
        float v0 = u0.x, v1 = u0.y, v2 = u1.x, v3 = u1.y, v4 = u2.x, v5 = u2.y;
        float m = fmaxf(fmaxf(fmaxf(v0, v1), fmaxf(v2, v3)), fmaxf(v4, v5));
        float e0 = __expf(v0 - m), e1 = __expf(v1 - m), e2 = __expf(v2 - m);
        float e3 = __expf(v3 - m), e4 = __expf(v4 - m), e5 = __expf(v5 - m);
        float sum = ((e0 + e1) + (e2 + e3)) + (e4 + e5);
        float r = fast_rcp(sum);
        float mine = (w12 == 0) ? e0 : (w12 == 1) ? e1 : (w12 == 2) ? e2
                   : (w12 == 3) ? e3 : (w12 == 4) ? e4 : e5;
        out[b * 6 + w12] = mine * r;
    }
}

extern "C" void kernel_launch(void* const* d_in, const int* in_sizes, int n_in,
                              void* d_out, int out_size, void* d_ws, size_t ws_size,
                              hipStream_t stream) {
    (void)in_sizes; (void)n_in; (void)d_ws; (void)ws_size; (void)out_size;
    const float* x    = (const float*)d_in[0];
    const float* Wih0 = (const float*)d_in[1];
    const float* Whh0 = (const float*)d_in[2];
    const float* bih0 = (const float*)d_in[3];
    const float* bhh0 = (const float*)d_in[4];
    const float* Wih1 = (const float*)d_in[5];
    const float* Whh1 = (const float*)d_in[6];
    const float* bih1 = (const float*)d_in[7];
    const float* bhh1 = (const float*)d_in[8];
    float* outp = (float*)d_out;

    // 2048 batch / 2 per wave = 1024 blocks of 64 threads = 1 wave per SIMD.
    stacked_lstm_kernel<<<1024, 64, 0, stream>>>(
        x, Wih0, Whh0, bih0, bhh0, Wih1, Whh1, bih1, bhh1, outp);
}